// Round 9
// baseline (603.345 us; speedup 1.0000x reference)
//
#include <hip/hip_runtime.h>
#include <hip/hip_cooperative_groups.h>
#include <cstddef>

namespace cg = cooperative_groups;

// Problem constants (B=4, S=2048, D=256, H=8, dh=32, d_ff=512), fp32 in/out.
constexpr int kB   = 4;
constexpr int kS   = 2048;
constexpr int kD   = 256;
constexpr int kH   = 8;
constexpr int kDH  = 32;
constexpr int kDFF = 512;
constexpr int kM   = kB * kS;   // 8192 token rows
constexpr float kEps = 1e-5f;
// 1/sqrt(32) * log2(e): scores pre-scaled so softmax uses exp2 directly.
constexpr float kScaleL2E = 0.17677669529663687f * 1.4426950408889634f;

typedef float f32x4  __attribute__((ext_vector_type(4)));
typedef short bf16x8 __attribute__((ext_vector_type(8)));
typedef unsigned short u16;
typedef unsigned int   u32;

__device__ inline u16 f2bf(float x) {
    union { float f; unsigned u; } c; c.f = x;
    const unsigned r = c.u + 0x7fffu + ((c.u >> 16) & 1u);
    return (u16)(r >> 16);
}

// pack two fp32 -> two bf16 (truncation) in ONE v_perm_b32.
__device__ inline u32 pk_trunc(float lo, float hi) {
    union { float f; u32 u; } a, b; a.f = lo; b.f = hi;
    return __builtin_amdgcn_perm(b.u, a.u, 0x07060302u);
}

// Shared scratch (u16): max(GEMM slab 32*260 = 8320, attn pbuf 4*32*72 = 9216)
constexpr int kSmemU16 = 9216;          // 18,432 B -> generous occupancy headroom

// ---------------------------------------------------------------------------
// LN: 8 rows per block-iteration, 2 rows/wave, 4 floats/lane, shuffle reduce.
// ---------------------------------------------------------------------------
__device__ __forceinline__
void ln_rows(const float* __restrict__ src, const float* __restrict__ g,
             const float* __restrict__ b, u16* __restrict__ dst,
             int bid, int tid, int nb)
{
    const int wave = tid >> 6;
    const int lane = tid & 63;
    const float4 g4 = *(const float4*)&g[lane * 4];
    const float4 b4 = *(const float4*)&b[lane * 4];
    for (int rb = bid; rb < kM / 8; rb += nb) {
        #pragma unroll
        for (int r = 0; r < 2; ++r) {
            const int row = rb * 8 + wave * 2 + r;
            const float4 v = *(const float4*)&src[(size_t)row * kD + lane * 4];
            float s1 = (v.x + v.y) + (v.z + v.w);
            float s2 = (v.x * v.x + v.y * v.y) + (v.z * v.z + v.w * v.w);
            #pragma unroll
            for (int off = 1; off < 64; off <<= 1) {
                s1 += __shfl_xor(s1, off);
                s2 += __shfl_xor(s2, off);
            }
            const float mu  = s1 * (1.0f / kD);
            const float var = s2 * (1.0f / kD) - mu * mu;
            const float inv = rsqrtf(var + kEps);
            *(ushort4*)&dst[(size_t)row * kD + lane * 4] = make_ushort4(
                f2bf((v.x - mu) * inv * g4.x + b4.x),
                f2bf((v.y - mu) * inv * g4.y + b4.y),
                f2bf((v.z - mu) * inv * g4.z + b4.z),
                f2bf((v.w - mu) * inv * g4.w + b4.w));
        }
    }
}

// ---------------------------------------------------------------------------
// GEMM: C = A @ W.T (+bias). A bf16 [M,KTOT]; W fp32 [N,KTOT] cast to bf16
// during LINEAR (fully coalesced) LDS staging, in 256-K chunks of a 32-row
// n-slab (slab 32x260 u16, 2-way bank aliasing = free). Tile 64(M) x 32(N),
// wave w owns rows [m0+16w,+16). Job-strided; job = (nblk*128 + mblk).
// OUTMODE: 0 = fp32 (+RES), 1 = SiLU->bf16, 2 = QKV split (Q pre-scaled,
// V pi-permuted: s' = (s&~63)|((s&15)*4+((s>>4)&3)), chunked [s'/8][dh][8]).
// ---------------------------------------------------------------------------
template<int OUTMODE, bool RES, int KTOT>
__device__ __forceinline__
void gemm_phase(const u16* __restrict__ A, const float* __restrict__ Wf,
                const float* __restrict__ bias, const float* __restrict__ res,
                float* __restrict__ Cf, u16* __restrict__ Cb,
                u16* __restrict__ KbP, u16* __restrict__ VtP,
                int N, int njobs, u16* smem, int bid, int tid, int nb)
{
    constexpr int BSTR = 260;
    constexpr int NCH  = KTOT / 256;
    const int wave = tid >> 6;
    const int lane = tid & 63;
    const int quad = lane >> 4;
    const int l16  = lane & 15;

    for (int job = bid; job < njobs; job += nb) {
        const int m0 = (job & 127) * 64;
        const int n0 = (job >> 7) * 32;

        f32x4 acc[2] = {};
        #pragma unroll
        for (int ch = 0; ch < NCH; ++ch) {
            __syncthreads();
            // ---- stage W[n0:n0+32, ch*256:+256) fp32 -> bf16, linear ----
            #pragma unroll
            for (int it = 0; it < 8; ++it) {
                const int e   = it * 1024 + tid * 4;
                const int row = e >> 8;
                const int col = e & 255;
                const float4 wv = *(const float4*)
                    &Wf[(size_t)(n0 + row) * KTOT + ch * 256 + col];
                *(ushort4*)&smem[row * BSTR + col] = make_ushort4(
                    f2bf(wv.x), f2bf(wv.y), f2bf(wv.z), f2bf(wv.w));
            }
            __syncthreads();

            const u16* arow = &A[(size_t)(m0 + wave * 16 + l16) * KTOT + ch * 256];
            #pragma unroll 4
            for (int k0 = 0; k0 < 256; k0 += 32) {
                const bf16x8 a = *(const bf16x8*)&arow[k0 + quad * 8];
                #pragma unroll
                for (int ni = 0; ni < 2; ++ni) {
                    const bf16x8 bf = *(const bf16x8*)
                        &smem[(ni * 16 + l16) * BSTR + k0 + quad * 8];
                    acc[ni] = __builtin_amdgcn_mfma_f32_16x16x32_bf16(a, bf, acc[ni], 0, 0, 0);
                }
            }
        }

        // ---- epilogue ----
        #pragma unroll
        for (int ni = 0; ni < 2; ++ni) {
            const float bias_v = bias[n0 + ni * 16 + l16];
            #pragma unroll
            for (int r = 0; r < 4; ++r) {
                const int m = m0 + wave * 16 + quad * 4 + r;
                float v = acc[ni][r] + bias_v;
                if (OUTMODE == 0) {
                    const int n = n0 + ni * 16 + l16;
                    if (RES) v += res[(size_t)m * N + n];
                    Cf[(size_t)m * N + n] = v;
                } else if (OUTMODE == 1) {
                    const int n = n0 + ni * 16 + l16;
                    v = v / (1.0f + __expf(-v));
                    Cb[(size_t)m * N + n] = f2bf(v);
                } else {
                    const int rgn = n0 >> 8;               // 0=Q 1=K 2=V
                    const int nl  = (n0 & 255) + ni * 16 + l16;
                    const int hh  = nl >> 5, dh = nl & 31;
                    const int bb  = m >> 11, s = m & (kS - 1);
                    const int bh  = bb * kH + hh;
                    if (rgn == 0)
                        Cb[((size_t)bh * kS + s) * kDH + dh] = f2bf(v * kScaleL2E);
                    else if (rgn == 1)
                        KbP[((size_t)bh * kS + s) * kDH + dh] = f2bf(v);
                    else {
                        const int sp = (s & ~63) | (((s & 15) << 2) | ((s >> 4) & 3));
                        VtP[(((size_t)bh * (kS / 8) + (sp >> 3)) * kDH + dh) * 8 + (sp & 7)] = f2bf(v);
                    }
                }
            }
        }
    }
}

// ---------------------------------------------------------------------------
// Attention (R6-proven math): 32 queries/wave, 2-way key split, pi-permuted
// P/V, no-max online softmax (scores O(1)), additive combine via LDS.
// Job decode: qblk = job&31, h = (job>>5)&7, b = job>>8; 1024 jobs.
// ---------------------------------------------------------------------------
constexpr int kPStrU = 72;   // P row stride in u16 (144 B)

__device__ __forceinline__
void attn_phase(const u16* __restrict__ Qb, const u16* __restrict__ Kb,
                const u16* __restrict__ Vp, u16* __restrict__ ctx,
                u16* smem, int bid, int tid, int nb)
{
    const int wave = tid >> 6;
    const int lane = tid & 63;
    const int quad = lane >> 4;
    const int l16  = lane & 15;
    const int qsub = wave >> 1;
    const int half = wave & 1;

    for (int job = bid; job < 1024; job += nb) {
        const int h = (job >> 5) & 7;
        const int b = job >> 8;
        const int bh = b * kH + h;
        const int q0 = (job & 31) * 64 + qsub * 32;

        __syncthreads();                    // smem reuse across jobs/phases

        bf16x8 aq[2];
        aq[0] = *(const bf16x8*)&Qb[((size_t)bh * kS + q0 + l16) * kDH + quad * 8];
        aq[1] = *(const bf16x8*)&Qb[((size_t)bh * kS + q0 + 16 + l16) * kDH + quad * 8];

        const u16* Kbase = Kb + (size_t)bh * kS * kDH;
        const u16* Vbase = Vp + (size_t)bh * kS * kDH;
        u16* pw = smem + wave * (32 * kPStrU);

        f32x4 O[2][2] = {};
        f32x4 lp[2] = {};
        const f32x4 zz = {0.f, 0.f, 0.f, 0.f};

        const int kbeg = half * (kS / 2);
        #pragma unroll 1
        for (int kt = kbeg; kt < kbeg + kS / 2; kt += 64) {
            bf16x8 kf[4];
            #pragma unroll
            for (int kg = 0; kg < 4; ++kg)
                kf[kg] = *(const bf16x8*)
                    &Kbase[(size_t)(kt + kg * 16 + l16) * kDH + quad * 8];
            bf16x8 vf[2][2];
            #pragma unroll
            for (int ks = 0; ks < 2; ++ks)
                #pragma unroll
                for (int nf = 0; nf < 2; ++nf)
                    vf[ks][nf] = *(const bf16x8*)
                        &Vbase[(size_t)((((kt + ks * 32 + quad * 8) >> 3) * kDH
                                         + nf * 16 + l16) << 3)];

            #pragma unroll
            for (int qb = 0; qb < 2; ++qb) {
                f32x4 S[4];
                #pragma unroll
                for (int kg = 0; kg < 4; ++kg)
                    S[kg] = __builtin_amdgcn_mfma_f32_16x16x32_bf16(aq[qb], kf[kg], zz, 0, 0, 0);
                #pragma unroll
                for (int r = 0; r < 4; ++r) {
                    const float e0 = exp2f(S[0][r]);
                    const float e1 = exp2f(S[1][r]);
                    const float e2 = exp2f(S[2][r]);
                    const float e3 = exp2f(S[3][r]);
                    lp[qb][r] += (e0 + e1) + (e2 + e3);
                    uint2 pk;
                    pk.x = pk_trunc(e0, e1);
                    pk.y = pk_trunc(e2, e3);
                    *(uint2*)&pw[(qb * 16 + quad * 4 + r) * kPStrU + l16 * 4] = pk;
                }
            }

            #pragma unroll
            for (int qb = 0; qb < 2; ++qb)
                #pragma unroll
                for (int ks = 0; ks < 2; ++ks) {
                    const bf16x8 pA = *(const bf16x8*)
                        &pw[(qb * 16 + l16) * kPStrU + ks * 32 + quad * 8];
                    O[qb][0] = __builtin_amdgcn_mfma_f32_16x16x32_bf16(pA, vf[ks][0], O[qb][0], 0, 0, 0);
                    O[qb][1] = __builtin_amdgcn_mfma_f32_16x16x32_bf16(pA, vf[ks][1], O[qb][1], 0, 0, 0);
                }
        }

        #pragma unroll
        for (int off = 1; off < 16; off <<= 1)
            #pragma unroll
            for (int qb = 0; qb < 2; ++qb)
                #pragma unroll
                for (int r = 0; r < 4; ++r)
                    lp[qb][r] += __shfl_xor(lp[qb][r], off);

        __syncthreads();                   // pbuf done; alias as combine buf
        float* cb = (float*)smem + qsub * (32 * 33);
        if (half == 1) {
            #pragma unroll
            for (int qb = 0; qb < 2; ++qb)
                #pragma unroll
                for (int r = 0; r < 4; ++r) {
                    const int row = qb * 16 + quad * 4 + r;
                    cb[row * 33 + l16]      = O[qb][0][r];
                    cb[row * 33 + 16 + l16] = O[qb][1][r];
                    if (l16 == 0) cb[row * 33 + 32] = lp[qb][r];
                }
        }
        __syncthreads();
        if (half == 0) {
            #pragma unroll
            for (int qb = 0; qb < 2; ++qb)
                #pragma unroll
                for (int r = 0; r < 4; ++r) {
                    const int row = qb * 16 + quad * 4 + r;
                    const float l   = lp[qb][r] + cb[row * 33 + 32];
                    const float inv = 1.0f / l;
                    const float o0 = O[qb][0][r] + cb[row * 33 + l16];
                    const float o1 = O[qb][1][r] + cb[row * 33 + 16 + l16];
                    const int q = q0 + row;
                    u16* crow = ctx + ((size_t)(b * kS + q)) * kD + h * kDH;
                    crow[l16]      = f2bf(o0 * inv);
                    crow[16 + l16] = f2bf(o1 * inv);
                }
        }
    }
}

struct KArgs {
    const float *x, *ln1g, *ln1b, *wqkv, *bqkv, *wproj, *bproj,
                *ln2g, *ln2b, *w1, *b1, *w2, *b2;
    float* out;
    u16 *y, *Qb, *Kb, *Vp, *ctx, *h;
};

// ---------------------------------------------------------------------------
// Cooperative whole-layer kernel: 7 phases, 6 grid.syncs.
// ---------------------------------------------------------------------------
__global__ __launch_bounds__(256, 4)
void encoder_kernel(KArgs a)
{
    __shared__ __align__(16) u16 smem[kSmemU16];
    cg::grid_group grid = cg::this_grid();
    const int bid = blockIdx.x, tid = threadIdx.x, nb = gridDim.x;

    ln_rows(a.x, a.ln1g, a.ln1b, a.y, bid, tid, nb);
    grid.sync();
    gemm_phase<2, false, 256>(a.y, a.wqkv, a.bqkv, nullptr,
                              nullptr, a.Qb, a.Kb, a.Vp, 0, 3072, smem, bid, tid, nb);
    grid.sync();
    attn_phase(a.Qb, a.Kb, a.Vp, a.ctx, smem, bid, tid, nb);
    grid.sync();
    gemm_phase<0, true, 256>(a.ctx, a.wproj, a.bproj, a.x,
                             a.out, nullptr, nullptr, nullptr, kD, 1024, smem, bid, tid, nb);
    grid.sync();
    ln_rows(a.out, a.ln2g, a.ln2b, a.y, bid, tid, nb);
    grid.sync();
    gemm_phase<1, false, 256>(a.y, a.w1, a.b1, nullptr,
                              nullptr, a.h, nullptr, nullptr, kDFF, 2048, smem, bid, tid, nb);
    grid.sync();
    gemm_phase<0, true, 512>(a.h, a.w2, a.b2, a.out,
                             a.out, nullptr, nullptr, nullptr, kD, 1024, smem, bid, tid, nb);
}

// ---------------------------------------------------------------------------
// Fallback plain kernels (same device code, 7 dispatches).
// ---------------------------------------------------------------------------
__global__ __launch_bounds__(256, 4)
void k_ln(const float* s, const float* g, const float* b, u16* d)
{ ln_rows(s, g, b, d, blockIdx.x, threadIdx.x, gridDim.x); }

template<int OUTMODE, bool RES, int KTOT>
__global__ __launch_bounds__(256, 4)
void k_gemm(const u16* A, const float* W, const float* bias, const float* res,
            float* Cf, u16* Cb, u16* KbP, u16* VtP, int N, int njobs)
{
    __shared__ __align__(16) u16 smem[32 * 260];
    gemm_phase<OUTMODE, RES, KTOT>(A, W, bias, res, Cf, Cb, KbP, VtP,
                                   N, njobs, smem, blockIdx.x, threadIdx.x, gridDim.x);
}

__global__ __launch_bounds__(256, 4)
void k_attn(const u16* Qb, const u16* Kb, const u16* Vp, u16* ctx)
{
    __shared__ __align__(16) u16 smem[kSmemU16];
    attn_phase(Qb, Kb, Vp, ctx, smem, blockIdx.x, threadIdx.x, gridDim.x);
}

// ---------------------------------------------------------------------------
// Workspace (bytes):
//   [ 0M, 4M)  Qb   (bf16)  -- [0,8M) reused as h after attn
//   [ 4M, 8M)  Kb   (bf16)
//   [ 8M,12M)  Vp   (bf16, pi-permuted chunked)
//   [12M,16M)  ctx  (bf16)
//   [16M,20M)  y    (bf16, LN1 then LN2)
// ---------------------------------------------------------------------------
extern "C" void kernel_launch(void* const* d_in, const int* in_sizes, int n_in,
                              void* d_out, int out_size, void* d_ws, size_t ws_size,
                              hipStream_t stream)
{
    char* ws = (char*)d_ws;
    KArgs a;
    a.x     = (const float*)d_in[0];
    a.ln1g  = (const float*)d_in[1];
    a.ln1b  = (const float*)d_in[2];
    a.wqkv  = (const float*)d_in[3];
    a.bqkv  = (const float*)d_in[4];
    a.wproj = (const float*)d_in[5];
    a.bproj = (const float*)d_in[6];
    a.ln2g  = (const float*)d_in[7];
    a.ln2b  = (const float*)d_in[8];
    a.w1    = (const float*)d_in[9];
    a.b1    = (const float*)d_in[10];
    a.w2    = (const float*)d_in[11];
    a.b2    = (const float*)d_in[12];
    a.out   = (float*)d_out;
    a.Qb    = (u16*)ws;
    a.Kb    = (u16*)(ws + ((size_t)4  << 20));
    a.Vp    = (u16*)(ws + ((size_t)8  << 20));
    a.ctx   = (u16*)(ws + ((size_t)12 << 20));
    a.y     = (u16*)(ws + ((size_t)16 << 20));
    a.h     = (u16*)ws;     // aliases Qb/Kb (dead after attention)

    // Grid sized to guaranteed co-residency (deterministic per context).
    int maxb = 0;
    (void)hipOccupancyMaxActiveBlocksPerMultiprocessor(&maxb, encoder_kernel, 256, 0);
    int grid = maxb * 256;
    if (grid > 1024) grid = 1024;

    hipError_t err = hipErrorUnknown;
    if (grid >= 256) {
        void* kargs[] = { (void*)&a };
        err = hipLaunchCooperativeKernel((const void*)encoder_kernel,
                                         dim3(grid), dim3(256), kargs, 0, stream);
    }
    if (err != hipSuccess) {
        (void)hipGetLastError();   // clear error state; use plain-dispatch path
        const dim3 blk(256);
        k_ln<<<dim3(1024), blk, 0, stream>>>(a.x, a.ln1g, a.ln1b, a.y);
        k_gemm<2, false, 256><<<dim3(3072), blk, 0, stream>>>(
            a.y, a.wqkv, a.bqkv, nullptr, nullptr, a.Qb, a.Kb, a.Vp, 0, 3072);
        k_attn<<<dim3(1024), blk, 0, stream>>>(a.Qb, a.Kb, a.Vp, a.ctx);
        k_gemm<0, true, 256><<<dim3(1024), blk, 0, stream>>>(
            a.ctx, a.wproj, a.bproj, a.x, a.out, nullptr, nullptr, nullptr, kD, 1024);
        k_ln<<<dim3(1024), blk, 0, stream>>>(a.out, a.ln2g, a.ln2b, a.y);
        k_gemm<1, false, 256><<<dim3(2048), blk, 0, stream>>>(
            a.y, a.w1, a.b1, nullptr, nullptr, a.h, nullptr, nullptr, kDFF, 2048);
        k_gemm<0, true, 512><<<dim3(1024), blk, 0, stream>>>(
            a.h, a.w2, a.b2, a.out, a.out, nullptr, nullptr, nullptr, kD, 1024);
    }
}

// Round 10
// 188.659 us; speedup vs baseline: 3.1981x; 3.1981x over previous
//
#include <hip/hip_runtime.h>
#include <cstddef>

// Problem constants (B=4, S=2048, D=256, H=8, dh=32, d_ff=512), fp32 in/out.
constexpr int kB   = 4;
constexpr int kS   = 2048;
constexpr int kD   = 256;
constexpr int kH   = 8;
constexpr int kDH  = 32;
constexpr int kDFF = 512;
constexpr int kM   = kB * kS;   // 8192 token rows
constexpr float kEps = 1e-5f;
// 1/sqrt(32) * log2(e): scores pre-scaled so softmax uses exp2 directly.
constexpr float kScaleL2E = 0.17677669529663687f * 1.4426950408889634f;

typedef float f32x4  __attribute__((ext_vector_type(4)));
typedef short bf16x8 __attribute__((ext_vector_type(8)));
typedef unsigned short u16;
typedef unsigned int   u32;

__device__ inline u16 f2bf(float x) {
    union { float f; unsigned u; } c; c.f = x;
    const unsigned r = c.u + 0x7fffu + ((c.u >> 16) & 1u);
    return (u16)(r >> 16);
}

// pack two fp32 -> two bf16 (truncation) in ONE v_perm_b32.
__device__ inline u32 pk_trunc(float lo, float hi) {
    union { float f; u32 u; } a, b; a.f = lo; b.f = hi;
    return __builtin_amdgcn_perm(b.u, a.u, 0x07060302u);
}

// ---------------------------------------------------------------------------
// LayerNorm: 4 rows/block, one wave per row, 4 floats/lane, pure-shuffle
// reduction. bf16 out. (R6-proven.)
// ---------------------------------------------------------------------------
__global__ __launch_bounds__(256)
void ln_kernel(const float* __restrict__ x, const float* __restrict__ g,
               const float* __restrict__ b, u16* __restrict__ y)
{
    const int wave = threadIdx.x >> 6;
    const int lane = threadIdx.x & 63;
    const int row  = blockIdx.x * 4 + wave;
    const float4 v = *(const float4*)&x[(size_t)row * kD + lane * 4];
    float s1 = (v.x + v.y) + (v.z + v.w);
    float s2 = (v.x * v.x + v.y * v.y) + (v.z * v.z + v.w * v.w);
    #pragma unroll
    for (int off = 1; off < 64; off <<= 1) {
        s1 += __shfl_xor(s1, off);
        s2 += __shfl_xor(s2, off);
    }
    const float mu  = s1 * (1.0f / kD);
    const float var = s2 * (1.0f / kD) - mu * mu;
    const float inv = rsqrtf(var + kEps);
    const float4 g4 = *(const float4*)&g[lane * 4];
    const float4 b4 = *(const float4*)&b[lane * 4];
    *(ushort4*)&y[(size_t)row * kD + lane * 4] = make_ushort4(
        f2bf((v.x - mu) * inv * g4.x + b4.x),
        f2bf((v.y - mu) * inv * g4.y + b4.y),
        f2bf((v.z - mu) * inv * g4.z + b4.z),
        f2bf((v.w - mu) * inv * g4.w + b4.w));
}

// ---------------------------------------------------------------------------
// bf16 MFMA NT GEMM (R6 shape): C = A @ W.T (+bias, epilogue variants).
// A bf16 [M,KTOT] from global; W **fp32** [N,KTOT], cast to bf16 during the
// fully-linear coalesced LDS staging (no separate cast pass). Whole K-slab
// staged once -> barrier-free K-loop. Tile 64(M) x NT(N), 4 waves, wave w
// owns rows [m0+16w,+16). LDS stride KTOT+4 (2-way bank aliasing = free).
// OUTMODE: 0 = fp32 (+RES), 1 = SiLU->bf16, 2 = QKV split:
//   Qb[bh][s][dh] (pre-scaled kScaleL2E), Kb[bh][s][dh],
//   Vp = pi8-permuted V within 128-key blocks: so = s&127,
//        p = (so&15)*8 + (so>>4); addr [bh][s/128][p/8][dh][p&7] (chunked 8).
// ---------------------------------------------------------------------------
template<int NT, int OUTMODE, bool RES, int KTOT>
__global__ __launch_bounds__(256)
void gemm_bf16(const u16* __restrict__ A, const float* __restrict__ Wf,
               const float* __restrict__ bias, const float* __restrict__ res,
               float* __restrict__ Cf, u16* __restrict__ Cb,
               u16* __restrict__ KbP, u16* __restrict__ VtP, int N)
{
    constexpr int BSTR = KTOT + 4;
    __shared__ u16 Bs[NT * BSTR];
    const int tid  = threadIdx.x;
    const int wave = tid >> 6;
    const int lane = tid & 63;
    const int quad = lane >> 4;
    const int l16  = lane & 15;
    const int m0 = blockIdx.x * 64;
    const int n0 = blockIdx.y * NT;

    // ---- stage W[n0:n0+NT, :] fp32 -> bf16, linear & coalesced ----
    {
        constexpr int ITS = (NT * KTOT) / 1024;
        #pragma unroll
        for (int it = 0; it < ITS; ++it) {
            const int e   = it * 1024 + tid * 4;
            const int row = e / KTOT;
            const int col = e & (KTOT - 1);
            const float4 wv = *(const float4*)&Wf[(size_t)(n0 + row) * KTOT + col];
            *(ushort4*)&Bs[row * BSTR + col] = make_ushort4(
                f2bf(wv.x), f2bf(wv.y), f2bf(wv.z), f2bf(wv.w));
        }
    }
    __syncthreads();

    f32x4 acc[NT / 16];
    #pragma unroll
    for (int ni = 0; ni < NT / 16; ++ni) acc[ni] = {0.f, 0.f, 0.f, 0.f};

    const u16* arow = &A[(size_t)(m0 + wave * 16 + l16) * KTOT];
    #pragma unroll 4
    for (int k0 = 0; k0 < KTOT; k0 += 32) {
        const bf16x8 a = *(const bf16x8*)&arow[k0 + quad * 8];
        #pragma unroll
        for (int ni = 0; ni < NT / 16; ++ni) {
            const bf16x8 bf = *(const bf16x8*)&Bs[(ni * 16 + l16) * BSTR + k0 + quad * 8];
            acc[ni] = __builtin_amdgcn_mfma_f32_16x16x32_bf16(a, bf, acc[ni], 0, 0, 0);
        }
    }

    // ---- epilogue ----
    #pragma unroll
    for (int ni = 0; ni < NT / 16; ++ni) {
        const float bias_v = bias[n0 + ni * 16 + l16];
        #pragma unroll
        for (int r = 0; r < 4; ++r) {
            const int m = m0 + wave * 16 + quad * 4 + r;
            float v = acc[ni][r] + bias_v;
            if (OUTMODE == 0) {
                const int n = n0 + ni * 16 + l16;
                if (RES) v += res[(size_t)m * N + n];
                Cf[(size_t)m * N + n] = v;
            } else if (OUTMODE == 1) {
                const int n = n0 + ni * 16 + l16;
                v = v / (1.0f + __expf(-v));
                Cb[(size_t)m * N + n] = f2bf(v);
            } else {
                const int rgn = n0 >> 8;               // 0=Q 1=K 2=V
                const int nl  = (n0 & 255) + ni * 16 + l16;
                const int hh  = nl >> 5, dh = nl & 31;
                const int bb  = m >> 11, s = m & (kS - 1);
                const int bh  = bb * kH + hh;
                if (rgn == 0)
                    Cb[((size_t)bh * kS + s) * kDH + dh] = f2bf(v * kScaleL2E);
                else if (rgn == 1)
                    KbP[((size_t)bh * kS + s) * kDH + dh] = f2bf(v);
                else {
                    const int so = s & 127;
                    const int p  = ((so & 15) << 3) | (so >> 4);   // pi8
                    VtP[((size_t)bh * (kS / 128) + (s >> 7)) * 4096
                        + (p >> 3) * 256 + dh * 8 + (p & 7)] = f2bf(v);
                }
            }
        }
    }
}

// ---------------------------------------------------------------------------
// MFMA flash attention v10: 32 queries/wave, 2-way key split, 128-key tiles.
// Block = 4 waves: wave = (qsub=wave>>1)*32 queries x (half=wave&1)*1024 keys,
// block covers 64 queries of one (b,h). Per 128-key tile:
//   - 8 coalesced K-frag loads (natural key order), 8 QK MFMAs per qb.
//   - p = exp2(s) (Q pre-scaled); lane's 8 values per row -> 4 v_perm packs
//     -> ONE ds_write_b128 at P col = l16*8+kg (pi8).
//   - V emitted pre-pi8-permuted by the QKV epilogue -> PV B-frag loads are
//     single coalesced 16-B loads; 16 PV MFMAs (P re-read as A-frags, b128).
// V-frag loads split into two batches (around the exp phase) to cap VGPR.
// No-max softmax (scores O(1)); halves combine by pure addition via LDS.
// Grid (16, 8, 4)... (kS/64=32, 8, 4) = 1024 blocks.
// ---------------------------------------------------------------------------
constexpr int kPStrU = 136;   // P row stride in u16 (272 B, 16B-aligned rows)

__global__ __launch_bounds__(256)
void attn_kernel(const u16* __restrict__ Qb, const u16* __restrict__ Kb,
                 const u16* __restrict__ Vp, u16* __restrict__ ctx)
{
    __shared__ __align__(16) u16 pbuf[4][32 * kPStrU];   // 34.8 KB; aliased later
    const int tid  = threadIdx.x;
    const int wave = tid >> 6;
    const int lane = tid & 63;
    const int quad = lane >> 4;
    const int l16  = lane & 15;
    const int h = blockIdx.y;
    const int b = blockIdx.z;
    const int bh = b * kH + h;
    const int qsub = wave >> 1;
    const int half = wave & 1;
    const int q0 = blockIdx.x * 64 + qsub * 32;

    bf16x8 aq[2];
    aq[0] = *(const bf16x8*)&Qb[((size_t)bh * kS + q0 + l16) * kDH + quad * 8];
    aq[1] = *(const bf16x8*)&Qb[((size_t)bh * kS + q0 + 16 + l16) * kDH + quad * 8];

    const u16* Kbase = Kb + (size_t)bh * kS * kDH;
    const u16* Vbase = Vp + (size_t)bh * kS * kDH;
    u16* pw = pbuf[wave];

    f32x4 O[2][2] = {};
    f32x4 lp[2] = {};
    const f32x4 zz = {0.f, 0.f, 0.f, 0.f};

    const int kbeg = half * (kS / 2);
    #pragma unroll 1
    for (int kt = kbeg; kt < kbeg + kS / 2; kt += 128) {
        // K-frags: natural key order, coalesced (16 consecutive rows x 64 B)
        bf16x8 kf[8];
        #pragma unroll
        for (int kg = 0; kg < 8; ++kg)
            kf[kg] = *(const bf16x8*)
                &Kbase[(size_t)(kt + kg * 16 + l16) * kDH + quad * 8];
        // V-frags batch 1 (ks 0..1): [block128][p/8=ks*4+quad][dh][8]
        const u16* vtile = Vbase + (size_t)(kt >> 7) * 4096;
        bf16x8 vf[4][2];
        #pragma unroll
        for (int ks = 0; ks < 2; ++ks)
            #pragma unroll
            for (int nf = 0; nf < 2; ++nf)
                vf[ks][nf] = *(const bf16x8*)
                    &vtile[(ks * 4 + quad) * 256 + (nf * 16 + l16) * 8];

        // QK + exp + P-pack/write per query sub-block
        #pragma unroll
        for (int qb = 0; qb < 2; ++qb) {
            f32x4 S[8];
            #pragma unroll
            for (int kg = 0; kg < 8; ++kg)
                S[kg] = __builtin_amdgcn_mfma_f32_16x16x32_bf16(aq[qb], kf[kg], zz, 0, 0, 0);
            #pragma unroll
            for (int r = 0; r < 4; ++r) {
                float e[8];
                #pragma unroll
                for (int kg = 0; kg < 8; ++kg) e[kg] = exp2f(S[kg][r]);
                lp[qb][r] += ((e[0] + e[1]) + (e[2] + e[3]))
                           + ((e[4] + e[5]) + (e[6] + e[7]));
                uint4 pk;
                pk.x = pk_trunc(e[0], e[1]);
                pk.y = pk_trunc(e[2], e[3]);
                pk.z = pk_trunc(e[4], e[5]);
                pk.w = pk_trunc(e[6], e[7]);
                // P col = l16*8 + kg (pi8): one b128 write per (qb,r)
                *(uint4*)&pw[(qb * 16 + quad * 4 + r) * kPStrU + l16 * 8] = pk;
            }
        }

        // V-frags batch 2 (ks 2..3)
        #pragma unroll
        for (int ks = 2; ks < 4; ++ks)
            #pragma unroll
            for (int nf = 0; nf < 2; ++nf)
                vf[ks][nf] = *(const bf16x8*)
                    &vtile[(ks * 4 + quad) * 256 + (nf * 16 + l16) * 8];

        // PV: P re-read as A-frags (stored col = pi8 position, matches V)
        #pragma unroll
        for (int qb = 0; qb < 2; ++qb)
            #pragma unroll
            for (int ks = 0; ks < 4; ++ks) {
                const bf16x8 pA = *(const bf16x8*)
                    &pw[(qb * 16 + l16) * kPStrU + ks * 32 + quad * 8];
                O[qb][0] = __builtin_amdgcn_mfma_f32_16x16x32_bf16(pA, vf[ks][0], O[qb][0], 0, 0, 0);
                O[qb][1] = __builtin_amdgcn_mfma_f32_16x16x32_bf16(pA, vf[ks][1], O[qb][1], 0, 0, 0);
            }
    }

    // per-row l: sum across the 16 lanes of each quad group
    #pragma unroll
    for (int off = 1; off < 16; off <<= 1)
        #pragma unroll
        for (int qb = 0; qb < 2; ++qb)
            #pragma unroll
            for (int r = 0; r < 4; ++r)
                lp[qb][r] += __shfl_xor(lp[qb][r], off);

    // ---- combine the two key-halves of each 32-query sub-block ----
    __syncthreads();                       // all pbuf traffic done; safe to alias
    float* cb = (float*)&pbuf[0][0] + qsub * (32 * 33);
    if (half == 1) {
        #pragma unroll
        for (int qb = 0; qb < 2; ++qb)
            #pragma unroll
            for (int r = 0; r < 4; ++r) {
                const int row = qb * 16 + quad * 4 + r;
                cb[row * 33 + l16]      = O[qb][0][r];
                cb[row * 33 + 16 + l16] = O[qb][1][r];
                if (l16 == 0) cb[row * 33 + 32] = lp[qb][r];
            }
    }
    __syncthreads();
    if (half == 0) {
        #pragma unroll
        for (int qb = 0; qb < 2; ++qb)
            #pragma unroll
            for (int r = 0; r < 4; ++r) {
                const int row = qb * 16 + quad * 4 + r;
                const float l   = lp[qb][r] + cb[row * 33 + 32];
                const float inv = 1.0f / l;
                const float o0 = O[qb][0][r] + cb[row * 33 + l16];
                const float o1 = O[qb][1][r] + cb[row * 33 + 16 + l16];
                const int q = q0 + row;
                u16* crow = ctx + ((size_t)(b * kS + q)) * kD + h * kDH;
                crow[l16]      = f2bf(o0 * inv);
                crow[16 + l16] = f2bf(o1 * inv);
            }
    }
}

// ---------------------------------------------------------------------------
// 7 dispatches: ln1 -> qkv -> attn -> proj(+res) -> ln2 -> ffn1(SiLU) ->
// ffn2(+res). Workspace (bytes):
//   [ 0M, 4M)  Qb   (bf16)  -- [0,8M) reused as h after attn
//   [ 4M, 8M)  Kb   (bf16)
//   [ 8M,12M)  Vp   (bf16, pi8-permuted chunked)
//   [12M,16M)  ctx  (bf16)
//   [16M,20M)  y    (bf16, LN1 then LN2)
// ---------------------------------------------------------------------------
extern "C" void kernel_launch(void* const* d_in, const int* in_sizes, int n_in,
                              void* d_out, int out_size, void* d_ws, size_t ws_size,
                              hipStream_t stream)
{
    const float* x      = (const float*)d_in[0];
    const float* ln1_g  = (const float*)d_in[1];
    const float* ln1_b  = (const float*)d_in[2];
    const float* w_qkv  = (const float*)d_in[3];
    const float* b_qkv  = (const float*)d_in[4];
    const float* w_proj = (const float*)d_in[5];
    const float* b_proj = (const float*)d_in[6];
    const float* ln2_g  = (const float*)d_in[7];
    const float* ln2_b  = (const float*)d_in[8];
    const float* w1     = (const float*)d_in[9];
    const float* b1     = (const float*)d_in[10];
    const float* w2     = (const float*)d_in[11];
    const float* b2     = (const float*)d_in[12];
    float* out = (float*)d_out;

    char* ws = (char*)d_ws;
    u16* Qb  = (u16*)ws;
    u16* Kb  = (u16*)(ws + ((size_t)4  << 20));
    u16* Vp  = (u16*)(ws + ((size_t)8  << 20));
    u16* ctx = (u16*)(ws + ((size_t)12 << 20));
    u16* y   = (u16*)(ws + ((size_t)16 << 20));
    u16* h   = (u16*)ws;                     // aliases Qb/Kb (dead after attn)

    const dim3 blk(256);

    // 1) y = bf16(LN1(x))
    ln_kernel<<<dim3(kM / 4), blk, 0, stream>>>(x, ln1_g, ln1_b, y);
    // 2) Qb/Kb/Vp = bf16(y @ w_qkv.T + b_qkv), Q pre-scaled, V pi8-permuted
    gemm_bf16<64, 2, false, 256><<<dim3(kM / 64, 12), blk, 0, stream>>>(
        y, w_qkv, b_qkv, nullptr, nullptr, Qb, Kb, Vp, 0);
    // 3) ctx = attention (bf16 out)
    attn_kernel<<<dim3(kS / 64, kH, kB), blk, 0, stream>>>(Qb, Kb, Vp, ctx);
    // 4) out = x + ctx @ w_proj.T + b_proj   (fp32)
    gemm_bf16<32, 0, true, 256><<<dim3(kM / 64, kD / 32), blk, 0, stream>>>(
        ctx, w_proj, b_proj, x, out, nullptr, nullptr, nullptr, kD);
    // 5) y = bf16(LN2(out))
    ln_kernel<<<dim3(kM / 4), blk, 0, stream>>>(out, ln2_g, ln2_b, y);
    // 6) h = bf16(silu(y @ w1.T + b1))
    gemm_bf16<64, 1, false, 256><<<dim3(kM / 64, kDFF / 64), blk, 0, stream>>>(
        y, w1, b1, nullptr, nullptr, h, nullptr, nullptr, kDFF);
    // 7) out = out + h @ w2.T + b2   (fp32, K=512)
    gemm_bf16<32, 0, true, 512><<<dim3(kM / 64, kD / 32), blk, 0, stream>>>(
        h, w2, b2, out, out, nullptr, nullptr, nullptr, kD);
}

// Round 11
// 184.572 us; speedup vs baseline: 3.2689x; 1.0221x over previous
//
#include <hip/hip_runtime.h>
#include <cstddef>

// Problem constants (B=4, S=2048, D=256, H=8, dh=32, d_ff=512), fp32 in/out.
constexpr int kB   = 4;
constexpr int kS   = 2048;
constexpr int kD   = 256;
constexpr int kH   = 8;
constexpr int kDH  = 32;
constexpr int kDFF = 512;
constexpr int kM   = kB * kS;   // 8192 token rows
constexpr float kEps = 1e-5f;
// 1/sqrt(32) * log2(e): scores pre-scaled so softmax uses exp2 directly.
constexpr float kScaleL2E = 0.17677669529663687f * 1.4426950408889634f;

typedef float f32x4  __attribute__((ext_vector_type(4)));
typedef short bf16x8 __attribute__((ext_vector_type(8)));
typedef unsigned short u16;
typedef unsigned int   u32;

__device__ inline u16 f2bf(float x) {
    union { float f; unsigned u; } c; c.f = x;
    const unsigned r = c.u + 0x7fffu + ((c.u >> 16) & 1u);
    return (u16)(r >> 16);
}

// pack two fp32 -> two bf16 (truncation) in ONE v_perm_b32.
__device__ inline u32 pk_trunc(float lo, float hi) {
    union { float f; u32 u; } a, b; a.f = lo; b.f = hi;
    return __builtin_amdgcn_perm(b.u, a.u, 0x07060302u);
}

// ---------------------------------------------------------------------------
// LayerNorm: 4 rows/block, one wave per row, 4 floats/lane, pure-shuffle
// reduction. bf16 out. (R6-proven.)
// ---------------------------------------------------------------------------
__global__ __launch_bounds__(256)
void ln_kernel(const float* __restrict__ x, const float* __restrict__ g,
               const float* __restrict__ b, u16* __restrict__ y)
{
    const int wave = threadIdx.x >> 6;
    const int lane = threadIdx.x & 63;
    const int row  = blockIdx.x * 4 + wave;
    const float4 v = *(const float4*)&x[(size_t)row * kD + lane * 4];
    float s1 = (v.x + v.y) + (v.z + v.w);
    float s2 = (v.x * v.x + v.y * v.y) + (v.z * v.z + v.w * v.w);
    #pragma unroll
    for (int off = 1; off < 64; off <<= 1) {
        s1 += __shfl_xor(s1, off);
        s2 += __shfl_xor(s2, off);
    }
    const float mu  = s1 * (1.0f / kD);
    const float var = s2 * (1.0f / kD) - mu * mu;
    const float inv = rsqrtf(var + kEps);
    const float4 g4 = *(const float4*)&g[lane * 4];
    const float4 b4 = *(const float4*)&b[lane * 4];
    *(ushort4*)&y[(size_t)row * kD + lane * 4] = make_ushort4(
        f2bf((v.x - mu) * inv * g4.x + b4.x),
        f2bf((v.y - mu) * inv * g4.y + b4.y),
        f2bf((v.z - mu) * inv * g4.z + b4.z),
        f2bf((v.w - mu) * inv * g4.w + b4.w));
}

// ---------------------------------------------------------------------------
// bf16 MFMA NT GEMM with M-loop: C = A @ W.T (+bias, epilogue variants).
// A bf16 [M,KTOT]; W fp32 [N,KTOT] cast to bf16 during linear coalesced LDS
// staging (once per block), then the block processes MLOOP consecutive
// 64-row m-tiles with NO further barriers (Bs is read-only).
// Tile 64(M) x NT(N), 4 waves, wave w owns rows [m0+16w,+16).
// LDS stride KTOT+4 (2-way bank aliasing = free).
// OUTMODE: 0 = fp32 (+RES), 1 = SiLU->bf16, 2 = QKV split:
//   Qb[bh][s][dh] (pre-scaled kScaleL2E), Kb[bh][s][dh],
//   Vp = pi-permuted V in 64-key blocks: s' = (s&~63)|((s&15)*4+((s>>4)&3)),
//        chunked [bh][s'/8][dh][8].
// ---------------------------------------------------------------------------
template<int NT, int OUTMODE, bool RES, int KTOT, int MLOOP>
__global__ __launch_bounds__(256)
void gemm_bf16(const u16* __restrict__ A, const float* __restrict__ Wf,
               const float* __restrict__ bias, const float* __restrict__ res,
               float* __restrict__ Cf, u16* __restrict__ Cb,
               u16* __restrict__ KbP, u16* __restrict__ VtP, int N)
{
    constexpr int BSTR = KTOT + 4;
    __shared__ u16 Bs[NT * BSTR];
    const int tid  = threadIdx.x;
    const int wave = tid >> 6;
    const int lane = tid & 63;
    const int quad = lane >> 4;
    const int l16  = lane & 15;
    const int mbase = blockIdx.x * (64 * MLOOP);
    const int n0 = blockIdx.y * NT;

    // ---- stage W[n0:n0+NT, :] fp32 -> bf16, linear & coalesced (once) ----
    {
        constexpr int ITS = (NT * KTOT) / 1024;
        #pragma unroll
        for (int it = 0; it < ITS; ++it) {
            const int e   = it * 1024 + tid * 4;
            const int row = e / KTOT;
            const int col = e & (KTOT - 1);
            const float4 wv = *(const float4*)&Wf[(size_t)(n0 + row) * KTOT + col];
            *(ushort4*)&Bs[row * BSTR + col] = make_ushort4(
                f2bf(wv.x), f2bf(wv.y), f2bf(wv.z), f2bf(wv.w));
        }
    }
    __syncthreads();

    #pragma unroll 1
    for (int mi = 0; mi < MLOOP; ++mi) {
        const int m0 = mbase + mi * 64;

        f32x4 acc[NT / 16];
        #pragma unroll
        for (int ni = 0; ni < NT / 16; ++ni) acc[ni] = {0.f, 0.f, 0.f, 0.f};

        const u16* arow = &A[(size_t)(m0 + wave * 16 + l16) * KTOT];
        #pragma unroll 4
        for (int k0 = 0; k0 < KTOT; k0 += 32) {
            const bf16x8 a = *(const bf16x8*)&arow[k0 + quad * 8];
            #pragma unroll
            for (int ni = 0; ni < NT / 16; ++ni) {
                const bf16x8 bf = *(const bf16x8*)&Bs[(ni * 16 + l16) * BSTR + k0 + quad * 8];
                acc[ni] = __builtin_amdgcn_mfma_f32_16x16x32_bf16(a, bf, acc[ni], 0, 0, 0);
            }
        }

        // ---- epilogue ----
        #pragma unroll
        for (int ni = 0; ni < NT / 16; ++ni) {
            const float bias_v = bias[n0 + ni * 16 + l16];
            #pragma unroll
            for (int r = 0; r < 4; ++r) {
                const int m = m0 + wave * 16 + quad * 4 + r;
                float v = acc[ni][r] + bias_v;
                if (OUTMODE == 0) {
                    const int n = n0 + ni * 16 + l16;
                    if (RES) v += res[(size_t)m * N + n];
                    Cf[(size_t)m * N + n] = v;
                } else if (OUTMODE == 1) {
                    const int n = n0 + ni * 16 + l16;
                    v = v / (1.0f + __expf(-v));
                    Cb[(size_t)m * N + n] = f2bf(v);
                } else {
                    const int rgn = n0 >> 8;               // 0=Q 1=K 2=V
                    const int nl  = (n0 & 255) + ni * 16 + l16;
                    const int hh  = nl >> 5, dh = nl & 31;
                    const int bb  = m >> 11, s = m & (kS - 1);
                    const int bh  = bb * kH + hh;
                    if (rgn == 0)
                        Cb[((size_t)bh * kS + s) * kDH + dh] = f2bf(v * kScaleL2E);
                    else if (rgn == 1)
                        KbP[((size_t)bh * kS + s) * kDH + dh] = f2bf(v);
                    else {
                        const int sp = (s & ~63) | (((s & 15) << 2) | ((s >> 4) & 3));
                        VtP[(((size_t)bh * (kS / 8) + (sp >> 3)) * kDH + dh) * 8 + (sp & 7)] = f2bf(v);
                    }
                }
            }
        }
    }
}

// ---------------------------------------------------------------------------
// MFMA flash attention v11: 32 queries/wave, 4-way key split, 64-key tiles.
// Block = 4 waves, ALL covering the same 32 queries of one (b,h); wave w
// processes key-quarter [w*512, +512). Per 64-key tile (R6-proven inner):
//   coalesced K-frag loads (natural key order), 8 QK MFMAs (2 qb x 4 kg);
//   p = exp2(s); lane's 4 values per row -> 2 v_perm -> ONE ds_write_b64 at
//   pi-permuted P col (c -> (c&15)*4 + (c>>4)); V emitted pre-pi-permuted ->
//   PV B-frag loads coalesced; 8 PV MFMAs (P as A-frags, b128 reads).
// No-max softmax (scores O(1)); quarters combine by PURE ADDITION: waves
// 1..3 park (O,l) in LDS, wave 0 sums, normalizes, stores ctx bf16.
// Grid (kS/32=64, 8, 4) = 2048 blocks -> 8/CU; LDS 18.4 KB, VGPR ~56 ->
// up to 8 blocks/CU co-resident (vs 4 before) for 2x latency hiding.
// ---------------------------------------------------------------------------
constexpr int kPStrU = 72;   // P row stride in u16 (144 B = 16B-aligned rows)

__global__ __launch_bounds__(256)
void attn_kernel(const u16* __restrict__ Qb, const u16* __restrict__ Kb,
                 const u16* __restrict__ Vp, u16* __restrict__ ctx)
{
    __shared__ __align__(16) u16 pbuf[4][32 * kPStrU];   // 18432 B; aliased later
    const int tid  = threadIdx.x;
    const int wave = tid >> 6;
    const int lane = tid & 63;
    const int quad = lane >> 4;
    const int l16  = lane & 15;
    const int h = blockIdx.y;
    const int b = blockIdx.z;
    const int bh = b * kH + h;
    const int q0 = blockIdx.x * 32;

    bf16x8 aq[2];
    aq[0] = *(const bf16x8*)&Qb[((size_t)bh * kS + q0 + l16) * kDH + quad * 8];
    aq[1] = *(const bf16x8*)&Qb[((size_t)bh * kS + q0 + 16 + l16) * kDH + quad * 8];

    const u16* Kbase = Kb + (size_t)bh * kS * kDH;
    const u16* Vbase = Vp + (size_t)bh * kS * kDH;
    u16* pw = pbuf[wave];

    f32x4 O[2][2] = {};
    f32x4 lp[2] = {};
    const f32x4 zz = {0.f, 0.f, 0.f, 0.f};

    const int kbeg = wave * (kS / 4);
    #pragma unroll 1
    for (int kt = kbeg; kt < kbeg + kS / 4; kt += 64) {
        // K-frags: natural key order, coalesced (16 consecutive rows x 64 B)
        bf16x8 kf[4];
        #pragma unroll
        for (int kg = 0; kg < 4; ++kg)
            kf[kg] = *(const bf16x8*)
                &Kbase[(size_t)(kt + kg * 16 + l16) * kDH + quad * 8];
        // V-frags: pi-permuted rows, chunk layout -> contiguous lanes
        bf16x8 vf[2][2];
        #pragma unroll
        for (int ks = 0; ks < 2; ++ks)
            #pragma unroll
            for (int nf = 0; nf < 2; ++nf)
                vf[ks][nf] = *(const bf16x8*)
                    &Vbase[(size_t)((((kt + ks * 32 + quad * 8) >> 3) * kDH
                                     + nf * 16 + l16) << 3)];

        #pragma unroll
        for (int qb = 0; qb < 2; ++qb) {
            f32x4 S[4];
            #pragma unroll
            for (int kg = 0; kg < 4; ++kg)
                S[kg] = __builtin_amdgcn_mfma_f32_16x16x32_bf16(aq[qb], kf[kg], zz, 0, 0, 0);
            // lane's 4 scores per row r are keys kg*16+l16 -> P cols l16*4+kg
            #pragma unroll
            for (int r = 0; r < 4; ++r) {
                const float e0 = exp2f(S[0][r]);
                const float e1 = exp2f(S[1][r]);
                const float e2 = exp2f(S[2][r]);
                const float e3 = exp2f(S[3][r]);
                lp[qb][r] += (e0 + e1) + (e2 + e3);
                uint2 pk;
                pk.x = pk_trunc(e0, e1);
                pk.y = pk_trunc(e2, e3);
                *(uint2*)&pw[(qb * 16 + quad * 4 + r) * kPStrU + l16 * 4] = pk;
            }
        }

        // PV: P re-read as A-frags (stored col = pi position, matches V)
        #pragma unroll
        for (int qb = 0; qb < 2; ++qb)
            #pragma unroll
            for (int ks = 0; ks < 2; ++ks) {
                const bf16x8 pA = *(const bf16x8*)
                    &pw[(qb * 16 + l16) * kPStrU + ks * 32 + quad * 8];
                O[qb][0] = __builtin_amdgcn_mfma_f32_16x16x32_bf16(pA, vf[ks][0], O[qb][0], 0, 0, 0);
                O[qb][1] = __builtin_amdgcn_mfma_f32_16x16x32_bf16(pA, vf[ks][1], O[qb][1], 0, 0, 0);
            }
    }

    // per-row l: sum across the 16 lanes of each quad group
    #pragma unroll
    for (int off = 1; off < 16; off <<= 1)
        #pragma unroll
        for (int qb = 0; qb < 2; ++qb)
            #pragma unroll
            for (int r = 0; r < 4; ++r)
                lp[qb][r] += __shfl_xor(lp[qb][r], off);

    // ---- combine the four key-quarters (pure addition) ----
    __syncthreads();                       // all pbuf traffic done; safe to alias
    float* cbase = (float*)&pbuf[0][0];    // 3 slots x 32 rows x 33 floats
    if (wave > 0) {
        float* cb = cbase + (wave - 1) * (32 * 33);
        #pragma unroll
        for (int qb = 0; qb < 2; ++qb)
            #pragma unroll
            for (int r = 0; r < 4; ++r) {
                const int row = qb * 16 + quad * 4 + r;
                cb[row * 33 + l16]      = O[qb][0][r];
                cb[row * 33 + 16 + l16] = O[qb][1][r];
                if (l16 == 0) cb[row * 33 + 32] = lp[qb][r];
            }
    }
    __syncthreads();
    if (wave == 0) {
        #pragma unroll
        for (int qb = 0; qb < 2; ++qb)
            #pragma unroll
            for (int r = 0; r < 4; ++r) {
                const int row = qb * 16 + quad * 4 + r;
                float l  = lp[qb][r];
                float o0 = O[qb][0][r];
                float o1 = O[qb][1][r];
                #pragma unroll
                for (int s = 0; s < 3; ++s) {
                    const float* cb = cbase + s * (32 * 33);
                    o0 += cb[row * 33 + l16];
                    o1 += cb[row * 33 + 16 + l16];
                    l  += cb[row * 33 + 32];
                }
                const float inv = 1.0f / l;
                const int q = q0 + row;
                u16* crow = ctx + ((size_t)(b * kS + q)) * kD + h * kDH;
                crow[l16]      = f2bf(o0 * inv);
                crow[16 + l16] = f2bf(o1 * inv);
            }
    }
}

// ---------------------------------------------------------------------------
// 7 dispatches: ln1 -> qkv -> attn -> proj(+res) -> ln2 -> ffn1(SiLU) ->
// ffn2(+res). Workspace (bytes):
//   [ 0M, 4M)  Qb   (bf16)  -- [0,8M) reused as h after attn
//   [ 4M, 8M)  Kb   (bf16)
//   [ 8M,12M)  Vp   (bf16, pi-permuted chunked)
//   [12M,16M)  ctx  (bf16)
//   [16M,20M)  y    (bf16, LN1 then LN2)
// ---------------------------------------------------------------------------
extern "C" void kernel_launch(void* const* d_in, const int* in_sizes, int n_in,
                              void* d_out, int out_size, void* d_ws, size_t ws_size,
                              hipStream_t stream)
{
    const float* x      = (const float*)d_in[0];
    const float* ln1_g  = (const float*)d_in[1];
    const float* ln1_b  = (const float*)d_in[2];
    const float* w_qkv  = (const float*)d_in[3];
    const float* b_qkv  = (const float*)d_in[4];
    const float* w_proj = (const float*)d_in[5];
    const float* b_proj = (const float*)d_in[6];
    const float* ln2_g  = (const float*)d_in[7];
    const float* ln2_b  = (const float*)d_in[8];
    const float* w1     = (const float*)d_in[9];
    const float* b1     = (const float*)d_in[10];
    const float* w2     = (const float*)d_in[11];
    const float* b2     = (const float*)d_in[12];
    float* out = (float*)d_out;

    char* ws = (char*)d_ws;
    u16* Qb  = (u16*)ws;
    u16* Kb  = (u16*)(ws + ((size_t)4  << 20));
    u16* Vp  = (u16*)(ws + ((size_t)8  << 20));
    u16* ctx = (u16*)(ws + ((size_t)12 << 20));
    u16* y   = (u16*)(ws + ((size_t)16 << 20));
    u16* h   = (u16*)ws;                     // aliases Qb/Kb (dead after attn)

    const dim3 blk(256);

    // 1) y = bf16(LN1(x))
    ln_kernel<<<dim3(kM / 4), blk, 0, stream>>>(x, ln1_g, ln1_b, y);
    // 2) Qb/Kb/Vp = bf16(y @ w_qkv.T + b_qkv), Q pre-scaled, V pi-permuted
    gemm_bf16<64, 2, false, 256, 2><<<dim3(kM / 128, 12), blk, 0, stream>>>(
        y, w_qkv, b_qkv, nullptr, nullptr, Qb, Kb, Vp, 0);
    // 3) ctx = attention (bf16 out), 4-way key split
    attn_kernel<<<dim3(kS / 32, kH, kB), blk, 0, stream>>>(Qb, Kb, Vp, ctx);
    // 4) out = x + ctx @ w_proj.T + b_proj   (fp32)
    gemm_bf16<32, 0, true, 256, 2><<<dim3(kM / 128, kD / 32), blk, 0, stream>>>(
        ctx, w_proj, b_proj, x, out, nullptr, nullptr, nullptr, kD);
    // 5) y = bf16(LN2(out))
    ln_kernel<<<dim3(kM / 4), blk, 0, stream>>>(out, ln2_g, ln2_b, y);
    // 6) h = bf16(silu(y @ w1.T + b1))
    gemm_bf16<64, 1, false, 256, 2><<<dim3(kM / 128, kDFF / 64), blk, 0, stream>>>(
        y, w1, b1, nullptr, nullptr, h, nullptr, nullptr, kDFF);
    // 7) out = out + h @ w2.T + b2   (fp32, K=512)
    gemm_bf16<32, 0, true, 512, 2><<<dim3(kM / 128, kD / 32), blk, 0, stream>>>(
        h, w2, b2, out, out, nullptr, nullptr, nullptr, kD);
}